// Round 6
// baseline (133.235 us; speedup 1.0000x reference)
//
#include <hip/hip_runtime.h>
#include <hip/hip_bf16.h>
#include <stdint.h>
#include <stddef.h>

// out[b, p*768+e] = sum_d x[b,d]*W[p,d]*GE[d,e] + bias[p]
// == per-b GEMM: OUT_b(256x768) = (x_b ⊙ W)(256x2000) @ GE(2000x768) + bias
// mask input redundant (weight pre-masked; mask exact 0/1). fp32 I/O.
//
// R6 changes vs R5 (GEMM at the ~850 TF 2-barrier plateau; LDS ds_read is the
// top pipe at ~52% of wall):
//  1. Wave tile 64x128 (4x8 frags), 2 waves/block of 128 threads. MFMA per
//     ds_read_b128 2.0 -> 2.67 (LDS/FLOP -25%), af-build/FLOP halved,
//     2-wave barriers. acc = 128 VGPR, __launch_bounds__(128,2).
//  2. pack_xw + transpose_ge merged into one prep dispatch (launch gap).
//
// Workspace: xb 64x2048 f16 (262144 B) | Wb 256x2048 f16 (1048576 B) |
// GT 768x2048 f16 (3145728 B) = 4,456,448 B total.

#define F_GENES 2000
#define KPAD    2048      // 32 * 64
#define P_PATH  256
#define EMB     768
#define BATCH   64
#define KSTEPS  32        // BK = 64

typedef _Float16 f16x8 __attribute__((ext_vector_type(8)));
typedef float    f32x4 __attribute__((ext_vector_type(4)));

__device__ __forceinline__ unsigned short f2h(float f) {
    union { _Float16 h; unsigned short s; } v; v.h = (_Float16)f; return v.s;
}

__device__ __forceinline__ void gload16(const void* g, void* l) {
    __builtin_amdgcn_global_load_lds((const __attribute__((address_space(1))) void*)g,
                                     (__attribute__((address_space(3))) void*)l,
                                     16, 0, 0);
}

// Prep (merged): blocks [0,320): pack x+W fp32->f16 K-padded to 2048.
//                blocks [320,1088): LDS-tiled transpose GE -> GT f16.
__global__ void prep_kernel(const float* __restrict__ x,
                            const float* __restrict__ w,
                            const float* __restrict__ ge,
                            unsigned short* __restrict__ xb,
                            unsigned short* __restrict__ wb,
                            unsigned short* __restrict__ GT) {
    __shared__ unsigned short tile[64][40];      // transpose scratch (16B rows)
    int t = threadIdx.x;
    if (blockIdx.x < 320) {
        int gid = blockIdx.x * 256 + t;          // (64+256)*256 = 81920 threads
        int row = gid >> 8;
        int s   = gid & 255;
        int d0  = s * 8;
        const float* src;
        unsigned short* dst;
        if (row < BATCH) { src = x + (size_t)row * F_GENES;           dst = xb + (size_t)row * KPAD; }
        else             { src = w + (size_t)(row - BATCH) * F_GENES; dst = wb + (size_t)(row - BATCH) * KPAD; }
        uint4 ov = make_uint4(0u, 0u, 0u, 0u);
        if (s < 250) {
            float4 v0 = *(const float4*)(src + d0);
            float4 v1 = *(const float4*)(src + d0 + 4);
            unsigned short* os = (unsigned short*)&ov;
            os[0] = f2h(v0.x); os[1] = f2h(v0.y); os[2] = f2h(v0.z); os[3] = f2h(v0.w);
            os[4] = f2h(v1.x); os[5] = f2h(v1.y); os[6] = f2h(v1.z); os[7] = f2h(v1.w);
        }
        *(uint4*)(dst + d0) = ov;
        return;
    }
    int bid = blockIdx.x - 320;
    int kt = bid & 63;                           // 64 k-tiles of 32 (kt=63 pure pad)
    int nt = bid >> 6;                           // 12 n-tiles of 64
    int k0 = kt * 32, n0 = nt * 64;
    int kr = t >> 4;                             // 0..15
    int nc = (t & 15) * 4;
#pragma unroll
    for (int p = 0; p < 2; ++p) {
        int k = k0 + p * 16 + kr;
        float4 v = make_float4(0.f, 0.f, 0.f, 0.f);
        if (k < F_GENES) v = *(const float4*)(ge + (size_t)k * EMB + n0 + nc);
        int kk = p * 16 + kr;
        tile[nc + 0][kk] = f2h(v.x);
        tile[nc + 1][kk] = f2h(v.y);
        tile[nc + 2][kk] = f2h(v.z);
        tile[nc + 3][kk] = f2h(v.w);
    }
    __syncthreads();
    int n  = t >> 2;
    int kc = (t & 3) * 8;
    uint4 o;
    unsigned short* os = (unsigned short*)&o;
#pragma unroll
    for (int j = 0; j < 8; ++j) os[j] = tile[n][kc + j];
    *(uint4*)(GT + (size_t)(n0 + n) * KPAD + k0 + kc) = o;
}

// GEMM (fused A): OUT(16384x768 fp32) = (x ⊙ W) @ GT^T + bias
// 128x128 block tile, 2 waves of 64x128 (4x8 frags 16x16x32 f16), BK=64,
// XOR-swizzled LDS (0 conflicts), global_load_lds width-16 staging.
__global__ __launch_bounds__(128, 2)
void gemm_kernel(const _Float16* __restrict__ xb, const _Float16* __restrict__ Wb,
                 const _Float16* __restrict__ GT, const float* __restrict__ bias,
                 float* __restrict__ out) {
    __shared__ __align__(16) _Float16 Ws[128 * 64];   // [m][k], rows of 8 swizzled chunks
    __shared__ __align__(16) _Float16 Bs[128 * 64];   // [n][k]

    const int tid  = threadIdx.x;
    const int w    = tid >> 6;              // wave 0/1 -> m-half
    const int l    = tid & 63;
    const int quad = l >> 4;
    const int ln   = l & 15;

    const int ct = blockIdx.x % 6;          // col tile (768/128)
    const int rt = blockIdx.x / 6;          // row tile (16384/128)
    const int b  = rt >> 1;                 // batch element (tile spans one b)
    const int p0 = (rt & 1) * 128;          // pathway base

    // staging: 8 passes x (2 waves x 8 rows); LDS slot (row, c) holds global
    // chunk c ^ (row&7) [XOR swizzle]. Lane l: row sub l>>3, slot l&7.
    const int srow   = l >> 3;
    const int schunk = (l & 7) ^ srow;
    const _Float16* Wg = Wb + (size_t)(p0 + w * 8 + srow) * KPAD + schunk * 8;
    const _Float16* Bg = GT + (size_t)(ct * 128 + w * 8 + srow) * KPAD + schunk * 8;
    _Float16* WsW = Ws + w * 512;           // + p*1024 per pass
    _Float16* BsW = Bs + w * 512;
    const _Float16* xg = xb + (size_t)b * KPAD + quad * 8;

    f32x4 acc[4][8] = {};

    for (int ks = 0; ks < KSTEPS; ++ks) {
#pragma unroll
        for (int p = 0; p < 8; ++p)
            gload16(Wg + p * 16 * KPAD, WsW + p * 1024);
#pragma unroll
        for (int p = 0; p < 8; ++p)
            gload16(Bg + p * 16 * KPAD, BsW + p * 1024);
        Wg += 64; Bg += 64;

        f16x8 xq0 = *(const f16x8*)xg;          // x[b, k0 + quad*8 ..]
        f16x8 xq1 = *(const f16x8*)(xg + 32);   // x[b, k0+32 + quad*8 ..]
        xg += 64;

        __syncthreads();                        // staging visible

#pragma unroll
        for (int h = 0; h < 2; ++h) {
            const f16x8 xq = h ? xq1 : xq0;
            const int sw = (((h * 4 + quad) ^ (ln & 7)) * 8);

            f16x8 af[4];
#pragma unroll
            for (int i = 0; i < 4; ++i) {
                f16x8 wf = *(const f16x8*)(Ws + (w * 64 + i * 16 + ln) * 64 + sw);
                af[i] = wf * xq;                // v_pk_mul_f16 — no cvts
            }
            f16x8 bfr[8];
#pragma unroll
            for (int i = 0; i < 8; ++i)
                bfr[i] = *(const f16x8*)(Bs + (i * 16 + ln) * 64 + sw);

#pragma unroll
            for (int mi = 0; mi < 4; ++mi)
#pragma unroll
                for (int ni = 0; ni < 8; ++ni)
                    acc[mi][ni] = __builtin_amdgcn_mfma_f32_16x16x32_f16(
                        af[mi], bfr[ni], acc[mi][ni], 0, 0, 0);
        }

        __syncthreads();                        // tile consumed
    }

    // epilogue: C/D layout col=ln, row=quad*4+reg (m89/m91-verified)
    const int rbase = rt * 128 + w * 64 + quad * 4;
    const int cbase = ct * 128 + ln;
#pragma unroll
    for (int mi = 0; mi < 4; ++mi) {
#pragma unroll
        for (int reg = 0; reg < 4; ++reg) {
            int r = rbase + mi * 16 + reg;
            float bv = bias[r & 255];           // p = r % 256
            size_t ro = (size_t)r * EMB;
#pragma unroll
            for (int ni = 0; ni < 8; ++ni)
                out[ro + cbase + ni * 16] = acc[mi][ni][reg] + bv;
        }
    }
}

extern "C" void kernel_launch(void* const* d_in, const int* in_sizes, int n_in,
                              void* d_out, int out_size, void* d_ws, size_t ws_size,
                              hipStream_t stream) {
    // inputs (fp32): x(64x2000), weight(256x2000), bias(256), mask(unused), ge(2000x768)
    const float* x    = (const float*)d_in[0];
    const float* wgt  = (const float*)d_in[1];
    const float* bias = (const float*)d_in[2];
    const float* ge   = (const float*)d_in[4];
    float* out = (float*)d_out;

    char* ws = (char*)d_ws;
    unsigned short* xbuf = (unsigned short*)ws;                        // 262144 B
    unsigned short* Wbuf = (unsigned short*)(ws + 262144);             // 1048576 B
    unsigned short* GTb  = (unsigned short*)(ws + 262144 + 1048576);   // 3145728 B

    prep_kernel<<<320 + 64 * 12, 256, 0, stream>>>(x, wgt, ge, xbuf, Wbuf, GTb);
    gemm_kernel<<<(16384 / 128) * (EMB / 128), 128, 0, stream>>>(
        (const _Float16*)xbuf, (const _Float16*)Wbuf, (const _Float16*)GTb, bias, out);
}